// Round 8
// baseline (207.790 us; speedup 1.0000x reference)
//
#include <hip/hip_runtime.h>

#define BB 32
#define TT 128
#define PP 512
#define DD 300
#define KT 10      // K-steps of 32 (KP = 320 = 300 data + bias slot + zeros)
#define KC 20      // k-chunks of 16 (2 per K-step)
#define NX 7168    // P * 14: full column set, native 14-stride scan layout
#define AT2 128    // A tiles of 32 rows (4096/32)
#define BT2 224    // B tiles of 32 cols (7168/32)
#define NEG -1e30f

typedef _Float16 half8 __attribute__((ext_vector_type(8)));
typedef float floatx16 __attribute__((ext_vector_type(16)));

__device__ __forceinline__ void async_load16(const void* g, void* l) {
    __builtin_amdgcn_global_load_lds(
        (const __attribute__((address_space(1))) void*)g,
        (__attribute__((address_space(3))) void*)l, 16, 0, 0);
}

__device__ __forceinline__ floatx16 mfma32(half8 a, half8 b, floatx16 c) {
    return __builtin_amdgcn_mfma_f32_32x32x16_f16(a, b, c, 0, 0, 0);
}

// ---------------------------------------------------------------------------
// Pack into 32x32x16-MFMA fragment-blocked layout + f16 Dekker split
// (x = hi + lo*2^-12, lo stored *4096). Chunk (tile32, kc16) = 1KB:
// half idx = lane*8+i, row = tile*32+(lane&31), k = kc*16+(lane>>5)*8+i.
// B rows = diags rows (all 14 cols/pattern; col 13 dead but kept for dense
// stride). K-slot 300 carries bias (A side gets exact 1.0); 301..319 zero.
// Same total buffer sizes as the 16x16 pack; only the blocking changed.
// ---------------------------------------------------------------------------
__global__ __launch_bounds__(256) void pack_kernel(
    const int* __restrict__ tokens, const float* __restrict__ emb,
    const float* __restrict__ diags, const float* __restrict__ bias,
    _Float16* __restrict__ AhP, _Float16* __restrict__ AlP,
    _Float16* __restrict__ BhP, _Float16* __restrict__ BlP)
{
    const int idx = blockIdx.x * 256 + threadIdx.x;
    if (idx >= (AT2 + BT2) * KC * 64) return;
    const int chunk = idx >> 6;
    const int ln = idx & 63;

    const float* src;
    float kslot;
    _Float16 *dh, *dl;
    int kc;
    if (chunk < AT2 * KC) {
        const int mt = chunk / KC; kc = chunk - mt * KC;
        const int m = mt * 32 + (ln & 31);
        src = emb + (size_t)tokens[m] * DD;
        kslot = 1.0f;
        dh = AhP + (size_t)chunk * 512 + ln * 8;
        dl = AlP + (size_t)chunk * 512 + ln * 8;
    } else {
        const int c2 = chunk - AT2 * KC;
        const int nt = c2 / KC; kc = c2 - nt * KC;
        const int n = nt * 32 + (ln & 31);       // srow = n directly
        src = diags + (size_t)n * DD;
        kslot = bias[n];
        dh = BhP + (size_t)c2 * 512 + ln * 8;
        dl = BlP + (size_t)c2 * 512 + ln * 8;
    }

    const int k0 = kc * 16 + (ln >> 5) * 8;
    float v[8];
    if (k0 + 8 <= DD) {
        float4 a = *(const float4*)(src + k0);
        float4 b = *(const float4*)(src + k0 + 4);
        v[0] = a.x; v[1] = a.y; v[2] = a.z; v[3] = a.w;
        v[4] = b.x; v[5] = b.y; v[6] = b.z; v[7] = b.w;
    } else {
        #pragma unroll
        for (int i = 0; i < 8; ++i) {
            const int k = k0 + i;
            v[i] = (k < DD) ? src[k] : (k == DD ? kslot : 0.f);
        }
    }
    half8 h, l;
    #pragma unroll
    for (int i = 0; i < 8; ++i) {
        h[i] = (_Float16)v[i];
        l[i] = (_Float16)((v[i] - (float)h[i]) * 4096.f);
    }
    *(half8*)dh = h;
    *(half8*)dl = l;
}

// ---------------------------------------------------------------------------
// GEMM (R8): proven 2-buffer schedule, 32x32x16 MFMA, redundancy-free A.
// C[m][n] = sum_k A[m][k]*B[n][k] (bias folded into k=300).
// R7 falsified the occupancy/latency theory (2x blocks/CU -> same 59us);
// the kernel is at the m97 instruction-mix ceiling. R8 changes the mix:
//  * 32x32x16 MFMA: same FLOP, HALF the MFMA instructions, +11% pipe
//    efficiency (m23 vs m64 ubench), floor 27 -> 22.6us.
//  * block = 128x128 = ONE batch element (blockIdx.y = b); wave w owns
//    32-row mtile w x all 128 cols -> A fragments unique per wave: the 2x
//    A-load redundancy of R0-R7 is gone (480 -> 324 KB global per block).
//  * B via LDS exactly as before: 16KB/kt staged with global_load_lds,
//    2-buffer, one __syncthreads per kt (schedule untouched).
//  * epilogue-only store guard (t < dl), divergent-safe post-loop.
// acc = 4 ntiles x 16 f32 x 2 (Dekker) = 128 VGPR; ~175 total; 2 blocks/CU.
// C/D layout 32x32 (m74/m101): col = lane&31, row = (r&3)+8*(r>>2)+4*(lane>>5).
// A/B operand layout (pattern-matched to verified 16x16x32): row = lane&31,
// k = (lane>>5)*8+i — both operands packed identically, as today.
// ---------------------------------------------------------------------------
__global__ __launch_bounds__(256, 2) void gemm_kernel(
    const _Float16* __restrict__ AhP, const _Float16* __restrict__ AlP,
    const _Float16* __restrict__ BhP, const _Float16* __restrict__ BlP,
    const int* __restrict__ doc_lens,
    float* __restrict__ C)
{
    __shared__ __align__(16) _Float16 Bs[2][2][2][4][512]; // [dbuf][q][h/l][nt][frag] 32KB

    const int tid = threadIdx.x;
    const int w = tid >> 6, ln = tid & 63;
    const int n0t = blockIdx.x * 4;        // 4 ntiles of 32 cols = 128 cols
    const int b = blockIdx.y;              // batch element; rows = t 0..127
    const int mtile = b * 4 + w;           // wave-owned 32-row A tile
    const int dl = doc_lens[b];            // in [64, 128]

    floatx16 acc0[4], acc1[4];
    #pragma unroll
    for (int nt = 0; nt < 4; ++nt) {
        #pragma unroll
        for (int e = 0; e < 16; ++e) { acc0[nt][e] = 0.f; acc1[nt][e] = 0.f; }
    }

    half8 ah[2][2], al[2][2];              // [pingpong][q]

    auto loadA = [&](int kt, int pb) {
        #pragma unroll
        for (int q = 0; q < 2; ++q) {      // 4 vmem ops, unique rows per wave
            const size_t ch = ((size_t)mtile * KC + 2 * kt + q) * 512 + ln * 8;
            ah[pb][q] = *(const half8*)(AhP + ch);
            al[pb][q] = *(const half8*)(AlP + ch);
        }
    };
    // 16 1KB chunks per kt (4 nt x 2 q x h/l) over 4 waves: wave w takes
    // q = w&1, hl = w>>1, nt = 0..3.
    const int sq = w & 1, shl = w >> 1;
    auto stageB = [&](int kt, int buf) {
        #pragma unroll
        for (int s = 0; s < 4; ++s) {
            const size_t ch = ((size_t)(n0t + s) * KC + 2 * kt + sq) * 512 + ln * 8;
            async_load16((shl ? BlP : BhP) + ch, &Bs[buf][sq][shl][s][0]);
        }
    };

    stageB(0, 0);
    loadA(0, 0);
    __syncthreads();

    #pragma unroll
    for (int kt = 0; kt < KT; ++kt) {
        const int cb = kt & 1, nb = cb ^ 1;
        if (kt + 1 < KT) {
            loadA(kt + 1, nb);
            stageB(kt + 1, nb);
        }
        #pragma unroll
        for (int nt = 0; nt < 4; ++nt) {
            #pragma unroll
            for (int q = 0; q < 2; ++q) {
                const half8 bh = *(const half8*)&Bs[cb][q][0][nt][ln * 8];
                const half8 bl = *(const half8*)&Bs[cb][q][1][nt][ln * 8];
                acc0[nt] = mfma32(ah[cb][q], bh, acc0[nt]);
                acc1[nt] = mfma32(ah[cb][q], bl, acc1[nt]);
                acc1[nt] = mfma32(al[cb][q], bh, acc1[nt]);
            }
        }
        __syncthreads();
    }

    // epilogue: 32x32 C/D layout col = lane&31, row = (r&3)+8*(r>>2)+4*(lane>>5).
    // store guard: row t = w*32 + rl; rows t >= dl never read by scan.
    const int t0 = w * 32;
    const int hi = (ln >> 5) * 4;
    #pragma unroll
    for (int nt = 0; nt < 4; ++nt) {
        const int n = (n0t + nt) * 32 + (ln & 31);
        #pragma unroll
        for (int r = 0; r < 16; ++r) {
            const int rl = (r & 3) + 8 * (r >> 2) + hi;
            const int t = t0 + rl;
            if (t < dl)
                C[(size_t)(b * TT + t) * NX + n] =
                    acc0[nt][r] + acc1[nt][r] * (1.0f / 4096.0f);
        }
    }
}

// ---------------------------------------------------------------------------
// Max-sum scan (proven structure, UNCHANGED).
// One thread per (b,p); 14-float 8B-aligned rows, 7x float2 loads, depth-4
// prefetch with STATIC slot indices; dl block-uniform. Rows t >= dl may be
// unwritten (gemm store guard) but are never consumed.
// v[0..6]=self-loop (diag0 l0..6), v[7..12]=main (diag1 l0..5), v[13] dead.
// ---------------------------------------------------------------------------
__global__ __launch_bounds__(64) void scan_kernel(
    const float* __restrict__ ts,
    const float* __restrict__ epsilons,
    const int* __restrict__ doc_lens,
    float* __restrict__ scores)
{
    const int b = blockIdx.x;
    const int p = blockIdx.y * 64 + threadIdx.x;
    const int dl = doc_lens[b];   // in [64, 128]

    float e[6];
    #pragma unroll
    for (int i = 0; i < 6; ++i) e[i] = epsilons[p * 6 + i];

    const float* base = ts + (size_t)b * TT * NX + p * 14;

    float h0 = 0.f, h1 = NEG, h2 = NEG, h3 = NEG, h4 = NEG, h5 = NEG, h6 = NEG;
    float sc = NEG;
    const bool end5 = (p < 256);

    float2 buf[4][7];

    auto load = [&](int slot, int t) {
        const float2* s = (const float2*)(base + (size_t)t * NX);
        #pragma unroll
        for (int i = 0; i < 7; ++i) buf[slot][i] = s[i];
    };
    auto step = [&](int slot) {
        const float2* v = buf[slot];
        float ae0 = h0;
        float ae1 = fmaxf(h1, h0 + e[0]);
        float ae2 = fmaxf(h2, h1 + e[1]);
        float ae3 = fmaxf(h3, h2 + e[2]);
        float ae4 = fmaxf(h4, h3 + e[3]);
        float ae5 = fmaxf(h5, h4 + e[4]);
        float ae6 = fmaxf(h6, h5 + e[5]);
        h0 = fmaxf(0.f,            ae0 + v[0].x);
        h1 = fmaxf(ae0 + v[3].y,   ae1 + v[0].y);
        h2 = fmaxf(ae1 + v[4].x,   ae2 + v[1].x);
        h3 = fmaxf(ae2 + v[4].y,   ae3 + v[1].y);
        h4 = fmaxf(ae3 + v[5].x,   ae4 + v[2].x);
        h5 = fmaxf(ae4 + v[5].y,   ae5 + v[2].y);
        h6 = fmaxf(ae5 + v[6].x,   ae6 + v[3].x);
        sc = fmaxf(sc, end5 ? h5 : h6);   // every executed step has t < dl
    };

    #pragma unroll
    for (int j = 0; j < 4; ++j) load(j, j);

    int tb = 0;
    for (; tb + 4 <= dl; tb += 4) {
        #pragma unroll
        for (int j = 0; j < 4; ++j) {
            step(j);
            const int t = tb + j + 4;
            load(j, t > 127 ? 127 : t);   // clamp: slots past dl never consumed
        }
    }
    const int rem = dl - tb;       // 0..3, block-uniform
    #pragma unroll
    for (int j = 0; j < 3; ++j)
        if (j < rem) step(j);

    scores[p * BB + b] = sc;
}

// ---------------------------------------------------------------------------
// BatchNorm (batch stats) + sign(relu) + final linear. One block. UNCHANGED.
// ---------------------------------------------------------------------------
__global__ __launch_bounds__(512) void finalize_kernel(
    const float* __restrict__ scores,
    const float* __restrict__ bn_w,
    const float* __restrict__ bn_b,
    const float* __restrict__ fw,
    const float* __restrict__ fb,
    float* __restrict__ out)
{
    __shared__ float acc[64];
    const int p = threadIdx.x;
    if (p < 64) acc[p] = 0.f;
    __syncthreads();

    float x[32];
    const float4* sp = (const float4*)(scores + p * 32);
    #pragma unroll
    for (int i = 0; i < 8; ++i) ((float4*)x)[i] = sp[i];

    float mean = 0.f;
    #pragma unroll
    for (int i = 0; i < 32; ++i) mean += x[i];
    mean *= (1.f / 32.f);
    float var = 0.f;
    #pragma unroll
    for (int i = 0; i < 32; ++i) { const float d = x[i] - mean; var = fmaf(d, d, var); }
    var *= (1.f / 32.f);

    const float scale = (1.f / sqrtf(var + 1e-5f)) * bn_w[p];
    const float shift = bn_b[p];
    const float w0 = fw[p], w1 = fw[PP + p];

    for (int b = 0; b < 32; ++b) {
        const float v = (x[b] - mean) * scale + shift;
        const bool bin = v > 0.f;
        float v0 = bin ? w0 : 0.f;
        float v1 = bin ? w1 : 0.f;
        #pragma unroll
        for (int o = 32; o; o >>= 1) {
            v0 += __shfl_xor(v0, o);
            v1 += __shfl_xor(v1, o);
        }
        if ((threadIdx.x & 63) == 0) {
            atomicAdd(&acc[b * 2 + 0], v0);
            atomicAdd(&acc[b * 2 + 1], v1);
        }
    }
    __syncthreads();
    if (p < 64) out[p] = acc[p] + fb[p & 1];
}

// ---------------------------------------------------------------------------
extern "C" void kernel_launch(void* const* d_in, const int* in_sizes, int n_in,
                              void* d_out, int out_size, void* d_ws, size_t ws_size,
                              hipStream_t stream) {
    const int*   tokens   = (const int*)d_in[0];
    const int*   doc_lens = (const int*)d_in[1];
    const float* emb      = (const float*)d_in[2];
    const float* diags    = (const float*)d_in[3];
    const float* bias     = (const float*)d_in[4];
    const float* eps      = (const float*)d_in[5];
    const float* bnw      = (const float*)d_in[6];
    const float* bnb      = (const float*)d_in[7];
    const float* fw       = (const float*)d_in[8];
    const float* fb       = (const float*)d_in[9];
    float* out = (float*)d_out;

    float* ts     = (float*)d_ws;                    // [4096][7168] = 117.4 MB
    float* scores = ts + (size_t)4096 * NX;          // [512][32]
    _Float16* AhP = (_Float16*)(scores + PP * BB);   // frag-blocked packs
    _Float16* AlP = AhP + (size_t)AT2 * KC * 512;
    _Float16* BhP = AlP + (size_t)AT2 * KC * 512;
    _Float16* BlP = BhP + (size_t)BT2 * KC * 512;

    pack_kernel<<<(AT2 + BT2) * KC * 64 / 256, 256, 0, stream>>>(
        tokens, emb, diags, bias, AhP, AlP, BhP, BlP);
    gemm_kernel<<<dim3(BT2 / 4, BB), 256, 0, stream>>>(
        AhP, AlP, BhP, BlP, doc_lens, ts);
    scan_kernel<<<dim3(BB, PP / 64), 64, 0, stream>>>(ts, eps, doc_lens, scores);
    finalize_kernel<<<1, 512, 0, stream>>>(scores, bnw, bnb, fw, fb, out);
}